// Round 6
// baseline (460.929 us; speedup 1.0000x reference)
//
#include <hip/hip_runtime.h>
#include <hip/hip_fp16.h>
#include <math.h>

#define N_NODES   50000
#define N_EDGES   1600000
#define E_TOT     (N_EDGES + N_NODES)
#define N_FEAT    128
#define HIDDEN    64
#define N_GRAPHS  128
#define NEG_SLOPE 0.2f
#define NB_SCAN   ((N_NODES + 1023) / 1024)
#define OCT_N     (N_NODES / 8)          // 6250, exact
#define FB_GRP    256                    // edge-slices per octant (2048 blocks)
#define FB_CE     ((N_EDGES + FB_GRP - 1) / FB_GRP)
#define EMB_B     ((N_NODES + 31) / 32)  // embed blocks (8 nodes/wave, 4 waves)
#define AGG_B     (N_NODES / 4)          // agg blocks (1 dst/wave)

// ---- monotone float<->uint encoding for atomicMax on floats ----
__device__ __forceinline__ unsigned fenc(float f) {
    unsigned u = __float_as_uint(f);
    return (u & 0x80000000u) ? ~u : (u | 0x80000000u);
}
__device__ __forceinline__ float fdec(unsigned k) {
    unsigned u = (k & 0x80000000u) ? (k & 0x7FFFFFFFu) : ~k;
    return __uint_as_float(u);
}
__device__ __forceinline__ float lrelu(float e) {
    return (e >= 0.f) ? e : NEG_SLOPE * e;
}

// ---- fold: W2C1 = w2 @ c1w ; B2C1 = b2 @ c1w (one block) ----
__global__ __launch_bounds__(256) void fold_w(
    const float* __restrict__ w2, const float* __restrict__ b2,
    const float* __restrict__ c1w,
    float* __restrict__ w2c1, float* __restrict__ b2c1)
{
    __shared__ float c1s[64 * 64];
    int tid = threadIdx.x;
    for (int i = tid; i < 4096; i += 256) c1s[i] = c1w[i];
    __syncthreads();
    int j = tid & 63, i0 = tid >> 6;
    for (int ii = 0; ii < 16; ++ii) {
        int i = i0 * 16 + ii;
        float a = 0.f;
#pragma unroll 8
        for (int k = 0; k < 64; ++k) a = fmaf(w2[i * 64 + k], c1s[k * 64 + j], a);
        w2c1[i * 64 + j] = a;
    }
    if (tid < 64) {
        float a = 0.f;
#pragma unroll 8
        for (int k = 0; k < 64; ++k) a = fmaf(b2[k], c1s[k * 64 + tid], a);
        b2c1[tid] = a;
    }
}

// ---- CSR count: real edges only (self-loops handled in scan) ----
__global__ void count_dst(const int* __restrict__ ei, unsigned* __restrict__ counts) {
    int e = blockIdx.x * 256 + threadIdx.x;
    if (e >= N_EDGES) return;
    int dst = __builtin_nontemporal_load(ei + N_EDGES + e);   // streaming, don't cache
    atomicAdd(&counts[dst], 1u);
}

// ---- two-level scan (counts+1 per node for the self-loop) ----
__global__ __launch_bounds__(1024) void scan_block(
    const unsigned* __restrict__ counts,
    unsigned* __restrict__ excl, unsigned* __restrict__ partial)
{
    __shared__ unsigned wt[16], wo[16];
    int tid = threadIdx.x, lane = tid & 63, wid = tid >> 6;
    int i = blockIdx.x * 1024 + tid;
    unsigned v = (i < N_NODES) ? (counts[i] + 1u) : 0u;
    unsigned xs = v;
#pragma unroll
    for (int off = 1; off < 64; off <<= 1) {
        unsigned t = __shfl_up(xs, off, 64);
        if (lane >= off) xs += t;
    }
    if (lane == 63) wt[wid] = xs;
    __syncthreads();
    if (tid == 0) {
        unsigned run = 0;
        for (int w = 0; w < 16; ++w) { wo[w] = run; run += wt[w]; }
        partial[blockIdx.x] = run;
    }
    __syncthreads();
    if (i < N_NODES) excl[i] = wo[wid] + xs - v;
}

// ---- finalize scan -> row_ptr & cursor; place self-loop; init pool ----
__global__ __launch_bounds__(256) void scan_add(
    const unsigned* __restrict__ excl, const unsigned* __restrict__ partial,
    unsigned* __restrict__ row_ptr, unsigned* __restrict__ cursor,
    int* __restrict__ csr_src, unsigned* __restrict__ g_enc)
{
    int tid = threadIdx.x, lane = tid & 63;
    int bg = blockIdx.x >> 2;                 // 1024-group index (uniform per block)
    unsigned pv = (lane < bg) ? partial[lane] : 0u;   // bg <= 48 < 64
#pragma unroll
    for (int off = 32; off; off >>= 1) pv += __shfl_xor(pv, off, 64);
    int i = blockIdx.x * 256 + tid;
    if (i < N_NODES) {
        unsigned r = excl[i] + pv;
        row_ptr[i] = r;
        csr_src[r] = i;          // self-loop occupies the first slot
        cursor[i]  = r + 1;
    }
    if (i == 0) row_ptr[N_NODES] = E_TOT;
    if (blockIdx.x == 0) {
        for (int j = tid; j < N_GRAPHS * HIDDEN; j += 256)
            g_enc[j] = fenc(-INFINITY);
    }
}

// ---- CSR fill, XCD-octant partitioned + nt reads (no L2 thrash) ----
__global__ __launch_bounds__(256) void fill_csr_oct(
    const int* __restrict__ ei,
    unsigned* __restrict__ cursor, int* __restrict__ csr_src)
{
    int oct = blockIdx.x & 7;        // round-robin XCD mapping
    int grp = blockIdx.x >> 3;
    int lo = oct * OCT_N, hi = lo + OCT_N;
    int beg = grp * FB_CE;
    int end = min(beg + FB_CE, N_EDGES);
    for (int base = beg; base < end; base += 256) {
        int e = base + threadIdx.x;
        if (e < end) {
            int dst = __builtin_nontemporal_load(ei + N_EDGES + e);
            if (dst >= lo && dst < hi) {
                int src = __builtin_nontemporal_load(ei + e);
                unsigned pos = atomicAdd(&cursor[dst], 1u);
                csr_src[pos] = src;   // stays in this XCD's L2, write-combines
            }
        }
    }
}

// ---- 1-block max-reduce of per-block maxima -> As[0] ----
__global__ __launch_bounds__(1024) void reduce_max(
    const float* __restrict__ in, int n, float* __restrict__ As)
{
    __shared__ float wm[16];
    int tid = threadIdx.x, lane = tid & 63, wid = tid >> 6;
    float m = -INFINITY;
    for (int i = tid; i < n; i += 1024) m = fmaxf(m, in[i]);
#pragma unroll
    for (int off = 32; off; off >>= 1) m = fmaxf(m, __shfl_xor(m, off, 64));
    if (lane == 0) wm[wid] = m;
    __syncthreads();
    if (tid == 0) {
        float r = -INFINITY;
        for (int w = 0; w < 16; ++w) r = fmaxf(r, wm[w]);
        As[0] = r;
    }
}

// ---- fused: node MLP + folded (w2@c1w) linear + alpha dots, 8 nodes/wave ----
__global__ __launch_bounds__(256) void embed_gemm1(
    const float* __restrict__ x,
    const float* __restrict__ n_w1, const float* __restrict__ n_b1,
    const float* __restrict__ w2c1, const float* __restrict__ b2c1,
    const float* __restrict__ a1s, const float* __restrict__ a1d,
    __half* __restrict__ hlo, __half* __restrict__ hhi,
    float* __restrict__ asrc, float* __restrict__ adst,
    float* __restrict__ blkmax)
{
    __shared__ float wred[4];
    int lane = threadIdx.x & 63, w = threadIdx.x >> 6;
    int n0 = blockIdx.x * 32 + w * 8;
    if (n0 < N_NODES) {
        float acc[8];
        float b1v = n_b1[lane];
#pragma unroll
        for (int nn = 0; nn < 8; ++nn) acc[nn] = b1v;
        const float* xb = x + (size_t)n0 * N_FEAT;
#pragma unroll 4
        for (int k = 0; k < N_FEAT; ++k) {
            float wv = n_w1[k * 64 + lane];
#pragma unroll
            for (int nn = 0; nn < 8; ++nn)
                acc[nn] = fmaf(xb[(size_t)nn * N_FEAT + k], wv, acc[nn]);
        }
#pragma unroll
        for (int nn = 0; nn < 8; ++nn) acc[nn] = fmaxf(acc[nn], 0.f);
        float hl[8];
        float bcv = b2c1[lane];
#pragma unroll
        for (int nn = 0; nn < 8; ++nn) hl[nn] = bcv;
        for (int k = 0; k < 64; ++k) {
            float wv = w2c1[k * 64 + lane];
#pragma unroll
            for (int nn = 0; nn < 8; ++nn)
                hl[nn] = fmaf(__shfl(acc[nn], k, 64), wv, hl[nn]);
        }
        float s1v = a1s[lane], d1v = a1d[lane];
        float wmax = -INFINITY;
#pragma unroll
        for (int nn = 0; nn < 8; ++nn) {
            int n = n0 + nn;
            if (lane < 32) hlo[(size_t)n * 32 + lane]        = __float2half(hl[nn]);
            else           hhi[(size_t)n * 32 + (lane - 32)] = __float2half(hl[nn]);
            float ps = hl[nn] * s1v, pd = hl[nn] * d1v;
#pragma unroll
            for (int off = 32; off; off >>= 1) {
                ps += __shfl_xor(ps, off, 64);
                pd += __shfl_xor(pd, off, 64);
            }
            if (lane == 0) { asrc[n] = ps; adst[n] = pd; wmax = fmaxf(wmax, ps); }
        }
        if (lane == 0) wred[w] = wmax;
    } else if ((threadIdx.x & 63) == 0) wred[w] = -INFINITY;
    __syncthreads();
    if (threadIdx.x == 0)
        blkmax[blockIdx.x] = fmaxf(fmaxf(wred[0], wred[1]), fmaxf(wred[2], wred[3]));
}

// ---- half-feature weighted aggregation; 2 edges/iter (lane = 32*p + f) ----
__device__ __forceinline__ float agg_half(
    const __half* __restrict__ hmat,      // [N][32] half array for this half
    const float* __restrict__ asrc,
    const int* __restrict__ csr_src, int s0, int s1, float ad, float C,
    int lane, float& den_out)
{
    int f31 = lane & 31;
    int p = lane >> 5;
    float acc0 = 0.f, acc1 = 0.f, acc2 = 0.f, acc3 = 0.f, sden = 0.f;
    for (int base = s0; base < s1; base += 64) {
        int i = base + lane;
        int idx = 0; float wgt = 0.f;
        if (i < s1) {
            idx = __builtin_nontemporal_load(csr_src + i);  // streamed once
            wgt = __expf(lrelu(asrc[idx] + ad) - C);
        }
        sden += wgt;
        int cnt = min(64, s1 - base);
        int j = 0;
        for (; j + 7 < cnt; j += 8) {       // 8 edges, 4 loads in flight
            int sa = __shfl(idx, j     + p, 64); float wa = __shfl(wgt, j     + p, 64);
            int sb = __shfl(idx, j + 2 + p, 64); float wb = __shfl(wgt, j + 2 + p, 64);
            int sc = __shfl(idx, j + 4 + p, 64); float wc = __shfl(wgt, j + 4 + p, 64);
            int sd = __shfl(idx, j + 6 + p, 64); float wd = __shfl(wgt, j + 6 + p, 64);
            acc0 = fmaf(wa, __half2float(hmat[(size_t)sa * 32 + f31]), acc0);
            acc1 = fmaf(wb, __half2float(hmat[(size_t)sb * 32 + f31]), acc1);
            acc2 = fmaf(wc, __half2float(hmat[(size_t)sc * 32 + f31]), acc2);
            acc3 = fmaf(wd, __half2float(hmat[(size_t)sd * 32 + f31]), acc3);
        }
        for (; j < cnt; j += 2) {           // tail; beyond-range staged slots wgt=0
            int sa = __shfl(idx, j + p, 64); float wa = __shfl(wgt, j + p, 64);
            acc0 = fmaf(wa, __half2float(hmat[(size_t)sa * 32 + f31]), acc0);
        }
    }
    float acc = acc0 + acc1 + acc2 + acc3;
    acc += __shfl_xor(acc, 32, 64);         // combine edge parities
#pragma unroll
    for (int off = 32; off; off >>= 1) sden += __shfl_xor(sden, off, 64);
    den_out = sden;
    return acc;
}

// ---- layer1 agg, low half: v_lo = relu(agg/den + c1b[f]) ----
__global__ __launch_bounds__(256) void agg1_lo(
    const __half* __restrict__ hlo1,
    const float* __restrict__ asrc, const float* __restrict__ adst,
    const unsigned* __restrict__ row_ptr, const int* __restrict__ csr_src,
    const float* __restrict__ As1, const float* __restrict__ c1b,
    float* __restrict__ v_lo)
{
    int lane = threadIdx.x & 63;
    int d = blockIdx.x * 4 + (threadIdx.x >> 6);
    int s0 = (int)row_ptr[d], s1 = (int)row_ptr[d + 1];
    float ad = adst[d];
    float C = lrelu(As1[0] + ad);
    float den;
    float acc = agg_half(hlo1, asrc, csr_src, s0, s1, ad, C, lane, den);
    if (lane < 32)
        v_lo[(size_t)d * 32 + lane] = fmaxf(acc / (den + 1e-30f) + c1b[lane], 0.f);
}

// ---- layer1 agg, high half + layer2 linear + alpha dots ----
__global__ __launch_bounds__(256) void agg1_hi(
    const __half* __restrict__ hhi1,
    const float* __restrict__ asrc, const float* __restrict__ adst,
    const unsigned* __restrict__ row_ptr, const int* __restrict__ csr_src,
    const float* __restrict__ As1, const float* __restrict__ c1b,
    const float* __restrict__ v_lo,
    const float* __restrict__ c2w, const float* __restrict__ a2s, const float* __restrict__ a2d,
    __half* __restrict__ hlo2, __half* __restrict__ hhi2,
    float* __restrict__ asrc2, float* __restrict__ adst2,
    float* __restrict__ blkmax)
{
    __shared__ float wred[4];
    int lane = threadIdx.x & 63, w = threadIdx.x >> 6;
    int d = blockIdx.x * 4 + w;
    int s0 = (int)row_ptr[d], s1 = (int)row_ptr[d + 1];
    float ad = adst[d];
    float C = lrelu(As1[0] + ad);
    float den;
    float acc = agg_half(hhi1, asrc, csr_src, s0, s1, ad, C, lane, den);
    float v_hi = fmaxf(acc / (den + 1e-30f) + c1b[32 + (lane & 31)], 0.f);
    float v = (lane < 32) ? v_lo[(size_t)d * 32 + lane] : v_hi;
    float hl = 0.f;
#pragma unroll 8
    for (int k = 0; k < 64; ++k)
        hl = fmaf(__shfl(v, k, 64), c2w[k * 64 + lane], hl);
    if (lane < 32) hlo2[(size_t)d * 32 + lane]        = __float2half(hl);
    else           hhi2[(size_t)d * 32 + (lane - 32)] = __float2half(hl);
    float ps = hl * a2s[lane], pd = hl * a2d[lane];
#pragma unroll
    for (int off = 32; off; off >>= 1) {
        ps += __shfl_xor(ps, off, 64);
        pd += __shfl_xor(pd, off, 64);
    }
    if (lane == 0) { asrc2[d] = ps; adst2[d] = pd; wred[w] = ps; }
    __syncthreads();
    if (threadIdx.x == 0)
        blkmax[blockIdx.x] = fmaxf(fmaxf(wred[0], wred[1]), fmaxf(wred[2], wred[3]));
}

// ---- layer2 agg half + bias + global max pool (half features) ----
template <int HALF>
__global__ __launch_bounds__(256) void agg2_pool(
    const __half* __restrict__ h2,
    const float* __restrict__ asrc, const float* __restrict__ adst,
    const unsigned* __restrict__ row_ptr, const int* __restrict__ csr_src,
    const float* __restrict__ As2, const float* __restrict__ c2b,
    const int* __restrict__ batch, unsigned* __restrict__ g_enc)
{
    int lane = threadIdx.x & 63;
    int d = blockIdx.x * 4 + (threadIdx.x >> 6);
    int s0 = (int)row_ptr[d], s1 = (int)row_ptr[d + 1];
    float ad = adst[d];
    float C = lrelu(As2[0] + ad);
    float den;
    float acc = agg_half(h2, asrc, csr_src, s0, s1, ad, C, lane, den);
    if (lane < 32) {
        float v = acc / (den + 1e-30f) + c2b[HALF * 32 + lane];
        atomicMax(&g_enc[batch[d] * 64 + HALF * 32 + lane], fenc(v));
    }
}

// ---- readout MLP: wave per graph ----
__global__ __launch_bounds__(256) void readout(
    const unsigned* __restrict__ g_enc,
    const float* __restrict__ fc1w, const float* __restrict__ fc1b,
    const float* __restrict__ fc2w, const float* __restrict__ fc2b,
    float* __restrict__ out)
{
    int lane = threadIdx.x & 63;
    int gi = blockIdx.x * 4 + (threadIdx.x >> 6);
    float gv = fdec(g_enc[gi * 64 + lane]);
    float a = fc1b[lane];
#pragma unroll 8
    for (int k = 0; k < 64; ++k)
        a = fmaf(__shfl(gv, k, 64), fc1w[k * 64 + lane], a);
    a = fmaxf(a, 0.f) * fc2w[lane];
#pragma unroll
    for (int off = 32; off; off >>= 1) a += __shfl_xor(a, off, 64);
    if (lane == 0) out[gi] = a + fc2b[0];
}

extern "C" void kernel_launch(void* const* d_in, const int* in_sizes, int n_in,
                              void* d_out, int out_size, void* d_ws, size_t ws_size,
                              hipStream_t stream)
{
    const float* x      = (const float*)d_in[0];
    const int*   ei     = (const int*)d_in[1];
    // d_in[2] edge_attr: dead value in reference, never read
    const int*   batch  = (const int*)d_in[3];
    const float* n_w1   = (const float*)d_in[4];
    const float* n_b1   = (const float*)d_in[5];
    const float* n_w2   = (const float*)d_in[6];
    const float* n_b2   = (const float*)d_in[7];
    // d_in[8..11] edge MLP weights: dead
    const float* c1_w    = (const float*)d_in[12];
    const float* c1_asrc = (const float*)d_in[13];
    const float* c1_adst = (const float*)d_in[14];
    const float* c1_b    = (const float*)d_in[15];
    const float* c2_w    = (const float*)d_in[16];
    const float* c2_asrc = (const float*)d_in[17];
    const float* c2_adst = (const float*)d_in[18];
    const float* c2_b    = (const float*)d_in[19];
    const float* fc1_w   = (const float*)d_in[20];
    const float* fc1_b   = (const float*)d_in[21];
    const float* fc2_w   = (const float*)d_in[22];
    const float* fc2_b   = (const float*)d_in[23];
    float* out = (float*)d_out;

    // workspace carve (256B aligned)
    char* ws = (char*)d_ws;
    size_t off = 0;
    auto alloc = [&](size_t bytes) -> void* {
        off = (off + 255) & ~(size_t)255;
        void* p = ws + off;
        off += bytes;
        return p;
    };
    unsigned* counts  = (unsigned*)alloc(sizeof(unsigned) * N_NODES);
    unsigned* excl    = (unsigned*)alloc(sizeof(unsigned) * N_NODES);
    unsigned* partial = (unsigned*)alloc(sizeof(unsigned) * (NB_SCAN + 1));
    unsigned* row_ptr = (unsigned*)alloc(sizeof(unsigned) * (N_NODES + 1));
    unsigned* cursor  = (unsigned*)alloc(sizeof(unsigned) * N_NODES);
    int*      csr_src = (int*)alloc(sizeof(int) * E_TOT);
    __half*   hlo1    = (__half*)alloc(sizeof(__half) * (size_t)N_NODES * 32);
    __half*   hhi1    = (__half*)alloc(sizeof(__half) * (size_t)N_NODES * 32);
    __half*   hlo2    = (__half*)alloc(sizeof(__half) * (size_t)N_NODES * 32);
    __half*   hhi2    = (__half*)alloc(sizeof(__half) * (size_t)N_NODES * 32);
    float*    v_lo    = (float*)alloc(sizeof(float) * (size_t)N_NODES * 32);
    float*    asrc1   = (float*)alloc(sizeof(float) * N_NODES);
    float*    adst1   = (float*)alloc(sizeof(float) * N_NODES);
    float*    asrc2   = (float*)alloc(sizeof(float) * N_NODES);
    float*    adst2   = (float*)alloc(sizeof(float) * N_NODES);
    unsigned* g_enc   = (unsigned*)alloc(sizeof(unsigned) * N_GRAPHS * HIDDEN);
    float*    w2c1    = (float*)alloc(sizeof(float) * 64 * 64);
    float*    b2c1    = (float*)alloc(sizeof(float) * 64);
    float*    blkmax1 = (float*)alloc(sizeof(float) * EMB_B);
    float*    blkmax2 = (float*)alloc(sizeof(float) * AGG_B);
    float*    As1     = (float*)alloc(sizeof(float) * 2);
    float*    As2     = (float*)alloc(sizeof(float) * 2);

    // CSR build + weight fold
    hipMemsetAsync(counts, 0, sizeof(unsigned) * N_NODES, stream);
    fold_w<<<1, 256, 0, stream>>>(n_w2, n_b2, c1_w, w2c1, b2c1);
    count_dst<<<(N_EDGES + 255) / 256, 256, 0, stream>>>(ei, counts);
    scan_block<<<NB_SCAN, 1024, 0, stream>>>(counts, excl, partial);
    scan_add<<<(N_NODES + 255) / 256, 256, 0, stream>>>(excl, partial, row_ptr, cursor,
                                                        csr_src, g_enc);
    fill_csr_oct<<<8 * FB_GRP, 256, 0, stream>>>(ei, cursor, csr_src);

    // fused pipeline
    embed_gemm1<<<EMB_B, 256, 0, stream>>>(
        x, n_w1, n_b1, w2c1, b2c1, c1_asrc, c1_adst,
        hlo1, hhi1, asrc1, adst1, blkmax1);
    reduce_max<<<1, 1024, 0, stream>>>(blkmax1, EMB_B, As1);
    agg1_lo<<<AGG_B, 256, 0, stream>>>(
        hlo1, asrc1, adst1, row_ptr, csr_src, As1, c1_b, v_lo);
    agg1_hi<<<AGG_B, 256, 0, stream>>>(
        hhi1, asrc1, adst1, row_ptr, csr_src, As1, c1_b, v_lo,
        c2_w, c2_asrc, c2_adst, hlo2, hhi2, asrc2, adst2, blkmax2);
    reduce_max<<<1, 1024, 0, stream>>>(blkmax2, AGG_B, As2);
    agg2_pool<0><<<AGG_B, 256, 0, stream>>>(
        hlo2, asrc2, adst2, row_ptr, csr_src, As2, c2_b, batch, g_enc);
    agg2_pool<1><<<AGG_B, 256, 0, stream>>>(
        hhi2, asrc2, adst2, row_ptr, csr_src, As2, c2_b, batch, g_enc);
    readout<<<N_GRAPHS / 4, 256, 0, stream>>>(g_enc, fc1_w, fc1_b, fc2_w, fc2_b, out);
}

// Round 7
// 383.256 us; speedup vs baseline: 1.2027x; 1.2027x over previous
//
#include <hip/hip_runtime.h>
#include <hip/hip_fp16.h>
#include <math.h>

#define N_NODES   50000
#define N_EDGES   1600000
#define E_TOT     (N_EDGES + N_NODES)
#define N_FEAT    128
#define HIDDEN    64
#define N_GRAPHS  128
#define NEG_SLOPE 0.2f
#define NB_SCAN   ((N_NODES + 1023) / 1024)
#define OCT_N     (N_NODES / 8)          // 6250, exact
#define FB_GRP    256                    // edge-slices per octant (2048 blocks)
#define FB_CE     ((N_EDGES + FB_GRP - 1) / FB_GRP)
#define EMB_B     ((N_NODES + 31) / 32)  // embed blocks (8 nodes/wave, 4 waves)
#define AGG_B     (N_NODES / 4)          // agg blocks (1 dst/wave)

// ---- monotone float<->uint encoding for atomicMax on floats ----
__device__ __forceinline__ unsigned fenc(float f) {
    unsigned u = __float_as_uint(f);
    return (u & 0x80000000u) ? ~u : (u | 0x80000000u);
}
__device__ __forceinline__ float fdec(unsigned k) {
    unsigned u = (k & 0x80000000u) ? (k & 0x7FFFFFFFu) : ~k;
    return __uint_as_float(u);
}
__device__ __forceinline__ float lrelu(float e) {
    return (e >= 0.f) ? e : NEG_SLOPE * e;
}
// ---- readlane: uniform-index broadcast to SGPR (no DS op, scalar fma operand)
__device__ __forceinline__ int rli(int v, int l) {
    return __builtin_amdgcn_readlane(v, l);
}
__device__ __forceinline__ float rlf(float v, int l) {
    return __int_as_float(__builtin_amdgcn_readlane(__float_as_int(v), l));
}

// ---- fold: W2C1 = w2 @ c1w ; B2C1 = b2 @ c1w (one block) ----
__global__ __launch_bounds__(256) void fold_w(
    const float* __restrict__ w2, const float* __restrict__ b2,
    const float* __restrict__ c1w,
    float* __restrict__ w2c1, float* __restrict__ b2c1)
{
    __shared__ float c1s[64 * 64];
    int tid = threadIdx.x;
    for (int i = tid; i < 4096; i += 256) c1s[i] = c1w[i];
    __syncthreads();
    int j = tid & 63, i0 = tid >> 6;
    for (int ii = 0; ii < 16; ++ii) {
        int i = i0 * 16 + ii;
        float a = 0.f;
#pragma unroll 8
        for (int k = 0; k < 64; ++k) a = fmaf(w2[i * 64 + k], c1s[k * 64 + j], a);
        w2c1[i * 64 + j] = a;
    }
    if (tid < 64) {
        float a = 0.f;
#pragma unroll 8
        for (int k = 0; k < 64; ++k) a = fmaf(b2[k], c1s[k * 64 + tid], a);
        b2c1[tid] = a;
    }
}

// ---- CSR count: real edges only (self-loops handled in scan) ----
__global__ void count_dst(const int* __restrict__ ei, unsigned* __restrict__ counts) {
    int e = blockIdx.x * 256 + threadIdx.x;
    if (e >= N_EDGES) return;
    int dst = __builtin_nontemporal_load(ei + N_EDGES + e);   // streaming
    atomicAdd(&counts[dst], 1u);
}

// ---- two-level scan (counts+1 per node for the self-loop) ----
__global__ __launch_bounds__(1024) void scan_block(
    const unsigned* __restrict__ counts,
    unsigned* __restrict__ excl, unsigned* __restrict__ partial)
{
    __shared__ unsigned wt[16], wo[16];
    int tid = threadIdx.x, lane = tid & 63, wid = tid >> 6;
    int i = blockIdx.x * 1024 + tid;
    unsigned v = (i < N_NODES) ? (counts[i] + 1u) : 0u;
    unsigned xs = v;
#pragma unroll
    for (int off = 1; off < 64; off <<= 1) {
        unsigned t = __shfl_up(xs, off, 64);
        if (lane >= off) xs += t;
    }
    if (lane == 63) wt[wid] = xs;
    __syncthreads();
    if (tid == 0) {
        unsigned run = 0;
        for (int w = 0; w < 16; ++w) { wo[w] = run; run += wt[w]; }
        partial[blockIdx.x] = run;
    }
    __syncthreads();
    if (i < N_NODES) excl[i] = wo[wid] + xs - v;
}

// ---- finalize scan -> row_ptr & cursor; place self-loop; init pool ----
__global__ __launch_bounds__(256) void scan_add(
    const unsigned* __restrict__ excl, const unsigned* __restrict__ partial,
    unsigned* __restrict__ row_ptr, unsigned* __restrict__ cursor,
    int* __restrict__ csr_src, unsigned* __restrict__ g_enc)
{
    int tid = threadIdx.x, lane = tid & 63;
    int bg = blockIdx.x >> 2;
    unsigned pv = (lane < bg) ? partial[lane] : 0u;   // bg <= 48 < 64
#pragma unroll
    for (int off = 32; off; off >>= 1) pv += __shfl_xor(pv, off, 64);
    int i = blockIdx.x * 256 + tid;
    if (i < N_NODES) {
        unsigned r = excl[i] + pv;
        row_ptr[i] = r;
        csr_src[r] = i;          // self-loop occupies the first slot
        cursor[i]  = r + 1;
    }
    if (i == 0) row_ptr[N_NODES] = E_TOT;
    if (blockIdx.x == 0) {
        for (int j = tid; j < N_GRAPHS * HIDDEN; j += 256)
            g_enc[j] = fenc(-INFINITY);
    }
}

// ---- CSR fill, XCD-octant partitioned + nt reads ----
__global__ __launch_bounds__(256) void fill_csr_oct(
    const int* __restrict__ ei,
    unsigned* __restrict__ cursor, int* __restrict__ csr_src)
{
    int oct = blockIdx.x & 7;        // round-robin XCD mapping
    int grp = blockIdx.x >> 3;
    int lo = oct * OCT_N, hi = lo + OCT_N;
    int beg = grp * FB_CE;
    int end = min(beg + FB_CE, N_EDGES);
    for (int base = beg; base < end; base += 256) {
        int e = base + threadIdx.x;
        if (e < end) {
            int dst = __builtin_nontemporal_load(ei + N_EDGES + e);
            if (dst >= lo && dst < hi) {
                int src = __builtin_nontemporal_load(ei + e);
                unsigned pos = atomicAdd(&cursor[dst], 1u);
                csr_src[pos] = src;
            }
        }
    }
}

// ---- 1-block max-reduce of per-block maxima -> As[0] ----
__global__ __launch_bounds__(1024) void reduce_max(
    const float* __restrict__ in, int n, float* __restrict__ As)
{
    __shared__ float wm[16];
    int tid = threadIdx.x, lane = tid & 63, wid = tid >> 6;
    float m = -INFINITY;
    for (int i = tid; i < n; i += 1024) m = fmaxf(m, in[i]);
#pragma unroll
    for (int off = 32; off; off >>= 1) m = fmaxf(m, __shfl_xor(m, off, 64));
    if (lane == 0) wm[wid] = m;
    __syncthreads();
    if (tid == 0) {
        float r = -INFINITY;
        for (int w = 0; w < 16; ++w) r = fmaxf(r, wm[w]);
        As[0] = r;
    }
}

// ---- fused: node MLP + folded (w2@c1w) linear + alpha dots, 8 nodes/wave ----
// x in per-lane registers, GEMMs via readlane broadcast (no DS, no uniform VMEM)
__global__ __launch_bounds__(256) void embed_gemm1(
    const float* __restrict__ x,
    const float* __restrict__ n_w1, const float* __restrict__ n_b1,
    const float* __restrict__ w2c1, const float* __restrict__ b2c1,
    const float* __restrict__ a1s, const float* __restrict__ a1d,
    __half* __restrict__ hlin,
    float* __restrict__ asrc, float* __restrict__ adst,
    float* __restrict__ blkmax)
{
    __shared__ float wred[4];
    int lane = threadIdx.x & 63, w = threadIdx.x >> 6;
    int n0 = blockIdx.x * 32 + w * 8;
    if (n0 < N_NODES) {      // 50000 % 8 == 0: whole 8-group in or out
        // coalesced per-lane x load: lane l holds x[n][l] and x[n][64+l]
        float xr0[8], xr1[8];
#pragma unroll
        for (int nn = 0; nn < 8; ++nn) {
            const float* xp = x + (size_t)(n0 + nn) * N_FEAT;
            xr0[nn] = xp[lane];
            xr1[nn] = xp[lane + 64];
        }
        float acc[8];
        float b1v = n_b1[lane];
#pragma unroll
        for (int nn = 0; nn < 8; ++nn) acc[nn] = b1v;
#pragma unroll 4
        for (int k = 0; k < 64; ++k) {
            float wv = n_w1[k * 64 + lane];
#pragma unroll
            for (int nn = 0; nn < 8; ++nn)
                acc[nn] = fmaf(rlf(xr0[nn], k), wv, acc[nn]);
        }
#pragma unroll 4
        for (int k = 0; k < 64; ++k) {
            float wv = n_w1[(k + 64) * 64 + lane];
#pragma unroll
            for (int nn = 0; nn < 8; ++nn)
                acc[nn] = fmaf(rlf(xr1[nn], k), wv, acc[nn]);
        }
#pragma unroll
        for (int nn = 0; nn < 8; ++nn) acc[nn] = fmaxf(acc[nn], 0.f);
        // folded second GEMM
        float hl[8];
        float bcv = b2c1[lane];
#pragma unroll
        for (int nn = 0; nn < 8; ++nn) hl[nn] = bcv;
#pragma unroll 4
        for (int k = 0; k < 64; ++k) {
            float wv = w2c1[k * 64 + lane];
#pragma unroll
            for (int nn = 0; nn < 8; ++nn)
                hl[nn] = fmaf(rlf(acc[nn], k), wv, hl[nn]);
        }
        float s1v = a1s[lane], d1v = a1d[lane];
        float wmax = -INFINITY;
#pragma unroll
        for (int nn = 0; nn < 8; ++nn) {
            int n = n0 + nn;
            hlin[(size_t)n * 64 + lane] = __float2half(hl[nn]);
            float ps = hl[nn] * s1v, pd = hl[nn] * d1v;
#pragma unroll
            for (int off = 32; off; off >>= 1) {
                ps += __shfl_xor(ps, off, 64);
                pd += __shfl_xor(pd, off, 64);
            }
            if (lane == 0) { asrc[n] = ps; adst[n] = pd; wmax = fmaxf(wmax, ps); }
        }
        if (lane == 0) wred[w] = wmax;
    } else if ((threadIdx.x & 63) == 0) wred[w] = -INFINITY;
    __syncthreads();
    if (threadIdx.x == 0)
        blkmax[blockIdx.x] = fmaxf(fmaxf(wred[0], wred[1]), fmaxf(wred[2], wred[3]));
}

// ---- full-row weighted aggregation: lane = feature, readlane idx/wgt ----
// gather base comes from SGPR (readlane) -> global_load_ushort with scalar base
__device__ __forceinline__ float agg_row(
    const __half* __restrict__ hmat,      // [N][64] fp16
    const float* __restrict__ asrc,
    const int* __restrict__ csr_src, int s0, int s1, float ad, float C,
    int lane, float& den_out)
{
    float acc0 = 0.f, acc1 = 0.f, acc2 = 0.f, acc3 = 0.f, sden = 0.f;
    for (int base = s0; base < s1; base += 64) {
        int i = base + lane;
        int idx = 0; float wgt = 0.f;
        if (i < s1) {
            idx = __builtin_nontemporal_load(csr_src + i);  // streamed once
            wgt = __expf(lrelu(asrc[idx] + ad) - C);
        }
        sden += wgt;
        int cnt = min(64, s1 - base);
        int j = 0;
        for (; j + 3 < cnt; j += 4) {        // 4 gathers in flight
            int sa = rli(idx, j);     float wa = rlf(wgt, j);
            int sb = rli(idx, j + 1); float wb = rlf(wgt, j + 1);
            int sc = rli(idx, j + 2); float wc = rlf(wgt, j + 2);
            int sd = rli(idx, j + 3); float wd = rlf(wgt, j + 3);
            acc0 = fmaf(wa, __half2float(hmat[(size_t)sa * 64 + lane]), acc0);
            acc1 = fmaf(wb, __half2float(hmat[(size_t)sb * 64 + lane]), acc1);
            acc2 = fmaf(wc, __half2float(hmat[(size_t)sc * 64 + lane]), acc2);
            acc3 = fmaf(wd, __half2float(hmat[(size_t)sd * 64 + lane]), acc3);
        }
        for (; j < cnt; ++j) {
            int sa = rli(idx, j); float wa = rlf(wgt, j);
            acc0 = fmaf(wa, __half2float(hmat[(size_t)sa * 64 + lane]), acc0);
        }
    }
#pragma unroll
    for (int off = 32; off; off >>= 1) sden += __shfl_xor(sden, off, 64);
    den_out = sden;
    return (acc0 + acc1) + (acc2 + acc3);
}

// ---- fused: GAT layer1 aggregate (+relu) + layer2 linear + alpha dots ----
__global__ __launch_bounds__(256) void agg1(
    const __half* __restrict__ hlin1,
    const float* __restrict__ asrc, const float* __restrict__ adst,
    const unsigned* __restrict__ row_ptr, const int* __restrict__ csr_src,
    const float* __restrict__ As1, const float* __restrict__ c1b,
    const float* __restrict__ c2w, const float* __restrict__ a2s, const float* __restrict__ a2d,
    __half* __restrict__ hlin2, float* __restrict__ asrc2, float* __restrict__ adst2,
    float* __restrict__ blkmax)
{
    __shared__ float wred[4];
    int lane = threadIdx.x & 63, w = threadIdx.x >> 6;
    int d = blockIdx.x * 4 + w;
    int s0 = (int)row_ptr[d], s1 = (int)row_ptr[d + 1];
    float ad = adst[d];
    float C = lrelu(As1[0] + ad);        // >= every edge's e (global asrc max)
    float den;
    float acc = agg_row(hlin1, asrc, csr_src, s0, s1, ad, C, lane, den);
    float v = fmaxf(acc / (den + 1e-30f) + c1b[lane], 0.f);   // + bias, relu
    // layer-2 linear via readlane
    float hl = 0.f;
#pragma unroll 8
    for (int k = 0; k < 64; ++k)
        hl = fmaf(rlf(v, k), c2w[k * 64 + lane], hl);
    hlin2[(size_t)d * 64 + lane] = __float2half(hl);
    float ps = hl * a2s[lane], pd = hl * a2d[lane];
#pragma unroll
    for (int off = 32; off; off >>= 1) {
        ps += __shfl_xor(ps, off, 64);
        pd += __shfl_xor(pd, off, 64);
    }
    if (lane == 0) { asrc2[d] = ps; adst2[d] = pd; wred[w] = ps; }
    __syncthreads();
    if (threadIdx.x == 0)
        blkmax[blockIdx.x] = fmaxf(fmaxf(wred[0], wred[1]), fmaxf(wred[2], wred[3]));
}

// ---- fused: GAT layer2 aggregate + bias + global max pool ----
__global__ __launch_bounds__(256) void agg2_pool(
    const __half* __restrict__ hlin2,
    const float* __restrict__ asrc, const float* __restrict__ adst,
    const unsigned* __restrict__ row_ptr, const int* __restrict__ csr_src,
    const float* __restrict__ As2, const float* __restrict__ c2b,
    const int* __restrict__ batch, unsigned* __restrict__ g_enc)
{
    int lane = threadIdx.x & 63;
    int d = blockIdx.x * 4 + (threadIdx.x >> 6);
    int s0 = (int)row_ptr[d], s1 = (int)row_ptr[d + 1];
    float ad = adst[d];
    float C = lrelu(As2[0] + ad);
    float den;
    float acc = agg_row(hlin2, asrc, csr_src, s0, s1, ad, C, lane, den);
    float v = acc / (den + 1e-30f) + c2b[lane];   // no relu
    atomicMax(&g_enc[batch[d] * 64 + lane], fenc(v));
}

// ---- readout MLP: wave per graph ----
__global__ __launch_bounds__(256) void readout(
    const unsigned* __restrict__ g_enc,
    const float* __restrict__ fc1w, const float* __restrict__ fc1b,
    const float* __restrict__ fc2w, const float* __restrict__ fc2b,
    float* __restrict__ out)
{
    int lane = threadIdx.x & 63;
    int gi = blockIdx.x * 4 + (threadIdx.x >> 6);
    float gv = fdec(g_enc[gi * 64 + lane]);
    float a = fc1b[lane];
#pragma unroll 8
    for (int k = 0; k < 64; ++k)
        a = fmaf(rlf(gv, k), fc1w[k * 64 + lane], a);
    a = fmaxf(a, 0.f) * fc2w[lane];
#pragma unroll
    for (int off = 32; off; off >>= 1) a += __shfl_xor(a, off, 64);
    if (lane == 0) out[gi] = a + fc2b[0];
}

extern "C" void kernel_launch(void* const* d_in, const int* in_sizes, int n_in,
                              void* d_out, int out_size, void* d_ws, size_t ws_size,
                              hipStream_t stream)
{
    const float* x      = (const float*)d_in[0];
    const int*   ei     = (const int*)d_in[1];
    // d_in[2] edge_attr: dead value in reference, never read
    const int*   batch  = (const int*)d_in[3];
    const float* n_w1   = (const float*)d_in[4];
    const float* n_b1   = (const float*)d_in[5];
    const float* n_w2   = (const float*)d_in[6];
    const float* n_b2   = (const float*)d_in[7];
    // d_in[8..11] edge MLP weights: dead
    const float* c1_w    = (const float*)d_in[12];
    const float* c1_asrc = (const float*)d_in[13];
    const float* c1_adst = (const float*)d_in[14];
    const float* c1_b    = (const float*)d_in[15];
    const float* c2_w    = (const float*)d_in[16];
    const float* c2_asrc = (const float*)d_in[17];
    const float* c2_adst = (const float*)d_in[18];
    const float* c2_b    = (const float*)d_in[19];
    const float* fc1_w   = (const float*)d_in[20];
    const float* fc1_b   = (const float*)d_in[21];
    const float* fc2_w   = (const float*)d_in[22];
    const float* fc2_b   = (const float*)d_in[23];
    float* out = (float*)d_out;

    // workspace carve (256B aligned)
    char* ws = (char*)d_ws;
    size_t off = 0;
    auto alloc = [&](size_t bytes) -> void* {
        off = (off + 255) & ~(size_t)255;
        void* p = ws + off;
        off += bytes;
        return p;
    };
    unsigned* counts  = (unsigned*)alloc(sizeof(unsigned) * N_NODES);
    unsigned* excl    = (unsigned*)alloc(sizeof(unsigned) * N_NODES);
    unsigned* partial = (unsigned*)alloc(sizeof(unsigned) * (NB_SCAN + 1));
    unsigned* row_ptr = (unsigned*)alloc(sizeof(unsigned) * (N_NODES + 1));
    unsigned* cursor  = (unsigned*)alloc(sizeof(unsigned) * N_NODES);
    int*      csr_src = (int*)alloc(sizeof(int) * E_TOT);
    __half*   hlin1   = (__half*)alloc(sizeof(__half) * (size_t)N_NODES * 64);
    __half*   hlin2   = (__half*)alloc(sizeof(__half) * (size_t)N_NODES * 64);
    float*    asrc1   = (float*)alloc(sizeof(float) * N_NODES);
    float*    adst1   = (float*)alloc(sizeof(float) * N_NODES);
    float*    asrc2   = (float*)alloc(sizeof(float) * N_NODES);
    float*    adst2   = (float*)alloc(sizeof(float) * N_NODES);
    unsigned* g_enc   = (unsigned*)alloc(sizeof(unsigned) * N_GRAPHS * HIDDEN);
    float*    w2c1    = (float*)alloc(sizeof(float) * 64 * 64);
    float*    b2c1    = (float*)alloc(sizeof(float) * 64);
    float*    blkmax1 = (float*)alloc(sizeof(float) * EMB_B);
    float*    blkmax2 = (float*)alloc(sizeof(float) * AGG_B);
    float*    As1     = (float*)alloc(sizeof(float) * 2);
    float*    As2     = (float*)alloc(sizeof(float) * 2);

    // CSR build + weight fold
    hipMemsetAsync(counts, 0, sizeof(unsigned) * N_NODES, stream);
    fold_w<<<1, 256, 0, stream>>>(n_w2, n_b2, c1_w, w2c1, b2c1);
    count_dst<<<(N_EDGES + 255) / 256, 256, 0, stream>>>(ei, counts);
    scan_block<<<NB_SCAN, 1024, 0, stream>>>(counts, excl, partial);
    scan_add<<<(N_NODES + 255) / 256, 256, 0, stream>>>(excl, partial, row_ptr, cursor,
                                                        csr_src, g_enc);
    fill_csr_oct<<<8 * FB_GRP, 256, 0, stream>>>(ei, cursor, csr_src);

    // fused pipeline
    embed_gemm1<<<EMB_B, 256, 0, stream>>>(
        x, n_w1, n_b1, w2c1, b2c1, c1_asrc, c1_adst,
        hlin1, asrc1, adst1, blkmax1);
    reduce_max<<<1, 1024, 0, stream>>>(blkmax1, EMB_B, As1);
    agg1<<<AGG_B, 256, 0, stream>>>(
        hlin1, asrc1, adst1, row_ptr, csr_src, As1,
        c1_b, c2_w, c2_asrc, c2_adst, hlin2, asrc2, adst2, blkmax2);
    reduce_max<<<1, 1024, 0, stream>>>(blkmax2, AGG_B, As2);
    agg2_pool<<<AGG_B, 256, 0, stream>>>(
        hlin2, asrc2, adst2, row_ptr, csr_src, As2, c2_b, batch, g_enc);
    readout<<<N_GRAPHS / 4, 256, 0, stream>>>(g_enc, fc1_w, fc1_b, fc2_w, fc2_b, out);
}

// Round 8
// 357.467 us; speedup vs baseline: 1.2894x; 1.0721x over previous
//
#include <hip/hip_runtime.h>
#include <hip/hip_fp16.h>
#include <math.h>

#define N_NODES   50000
#define N_EDGES   1600000
#define E_TOT     (N_EDGES + N_NODES)
#define N_FEAT    128
#define HIDDEN    64
#define N_GRAPHS  128
#define NEG_SLOPE 0.2f
#define NB_SCAN   ((N_NODES + 1023) / 1024)
#define OCT_N     (N_NODES / 8)            // 6250
#define EMB_B     ((N_NODES + 31) / 32)    // 1563 embed blocks (8 nodes/wave)
#define BUCKET_B  640                      // bucket blocks
#define BCHUNK    ((N_EDGES + BUCKET_B - 1) / BUCKET_B)   // 2500 edges/block
#define SB_CAP    576                      // LDS bucket capacity per octant
#define OCT_CAP   225000                   // per-octant global bucket capacity
#define FILL_GRP  128                      // scatter groups per octant
#define AGG_B     (N_NODES / 4)            // agg blocks (1 dst/wave)

// ---- monotone float<->uint encoding for atomicMax on floats ----
__device__ __forceinline__ unsigned fenc(float f) {
    unsigned u = __float_as_uint(f);
    return (u & 0x80000000u) ? ~u : (u | 0x80000000u);
}
__device__ __forceinline__ float fdec(unsigned k) {
    unsigned u = (k & 0x80000000u) ? (k & 0x7FFFFFFFu) : ~k;
    return __uint_as_float(u);
}
__device__ __forceinline__ float lrelu(float e) {
    return (e >= 0.f) ? e : NEG_SLOPE * e;
}
__device__ __forceinline__ int rli(int v, int l) {
    return __builtin_amdgcn_readlane(v, l);
}
__device__ __forceinline__ float rlf(float v, int l) {
    return __int_as_float(__builtin_amdgcn_readlane(__float_as_int(v), l));
}

// ---- fold: W2C1 = w2 @ c1w ; B2C1 = b2 @ c1w (one block) ----
__global__ __launch_bounds__(256) void fold_w(
    const float* __restrict__ w2, const float* __restrict__ b2,
    const float* __restrict__ c1w,
    float* __restrict__ w2c1, float* __restrict__ b2c1)
{
    __shared__ float c1s[64 * 64];
    int tid = threadIdx.x;
    for (int i = tid; i < 4096; i += 256) c1s[i] = c1w[i];
    __syncthreads();
    int j = tid & 63, i0 = tid >> 6;
    for (int ii = 0; ii < 16; ++ii) {
        int i = i0 * 16 + ii;
        float a = 0.f;
#pragma unroll 8
        for (int k = 0; k < 64; ++k) a = fmaf(w2[i * 64 + k], c1s[k * 64 + j], a);
        w2c1[i * 64 + j] = a;
    }
    if (tid < 64) {
        float a = 0.f;
#pragma unroll 8
        for (int k = 0; k < 64; ++k) a = fmaf(b2[k], c1s[k * 64 + tid], a);
        b2c1[tid] = a;
    }
}

// ---- FUSED: embed blocks [0,EMB_B) + edge-bucket blocks [EMB_B, EMB_B+BUCKET_B) ----
__global__ __launch_bounds__(256) void embed_bucket(
    const float* __restrict__ x,
    const float* __restrict__ n_w1, const float* __restrict__ n_b1,
    const float* __restrict__ w2c1, const float* __restrict__ b2c1,
    const float* __restrict__ a1s, const float* __restrict__ a1d,
    __half* __restrict__ hlin,
    float* __restrict__ asrc, float* __restrict__ adst,
    float* __restrict__ blkmax,
    const int* __restrict__ ei, unsigned* __restrict__ counts,
    unsigned* __restrict__ tail, unsigned long long* __restrict__ oct_buf)
{
    __shared__ unsigned long long sbuf[8][SB_CAP];
    __shared__ unsigned scnt[8];
    __shared__ unsigned sbase[8];
    int tid = threadIdx.x;

    if (blockIdx.x < EMB_B) {
        // ---------- embed path: node MLP + folded linear + alpha dots ----------
        float* wred = (float*)&sbuf[0][0];
        int lane = tid & 63, w = tid >> 6;
        int n0 = blockIdx.x * 32 + w * 8;
        if (n0 < N_NODES) {      // 50000 % 8 == 0: whole 8-group in or out
            float xr0[8], xr1[8];
#pragma unroll
            for (int nn = 0; nn < 8; ++nn) {
                const float* xp = x + (size_t)(n0 + nn) * N_FEAT;
                xr0[nn] = xp[lane];
                xr1[nn] = xp[lane + 64];
            }
            float acc[8];
            float b1v = n_b1[lane];
#pragma unroll
            for (int nn = 0; nn < 8; ++nn) acc[nn] = b1v;
#pragma unroll 4
            for (int k = 0; k < 64; ++k) {
                float wv = n_w1[k * 64 + lane];
#pragma unroll
                for (int nn = 0; nn < 8; ++nn)
                    acc[nn] = fmaf(rlf(xr0[nn], k), wv, acc[nn]);
            }
#pragma unroll 4
            for (int k = 0; k < 64; ++k) {
                float wv = n_w1[(k + 64) * 64 + lane];
#pragma unroll
                for (int nn = 0; nn < 8; ++nn)
                    acc[nn] = fmaf(rlf(xr1[nn], k), wv, acc[nn]);
            }
#pragma unroll
            for (int nn = 0; nn < 8; ++nn) acc[nn] = fmaxf(acc[nn], 0.f);
            float hl[8];
            float bcv = b2c1[lane];
#pragma unroll
            for (int nn = 0; nn < 8; ++nn) hl[nn] = bcv;
#pragma unroll 4
            for (int k = 0; k < 64; ++k) {
                float wv = w2c1[k * 64 + lane];
#pragma unroll
                for (int nn = 0; nn < 8; ++nn)
                    hl[nn] = fmaf(rlf(acc[nn], k), wv, hl[nn]);
            }
            float s1v = a1s[lane], d1v = a1d[lane];
            float wmax = -INFINITY;
#pragma unroll
            for (int nn = 0; nn < 8; ++nn) {
                int n = n0 + nn;
                hlin[(size_t)n * 64 + lane] = __float2half(hl[nn]);
                float ps = hl[nn] * s1v, pd = hl[nn] * d1v;
#pragma unroll
                for (int off = 32; off; off >>= 1) {
                    ps += __shfl_xor(ps, off, 64);
                    pd += __shfl_xor(pd, off, 64);
                }
                if (lane == 0) { asrc[n] = ps; adst[n] = pd; wmax = fmaxf(wmax, ps); }
            }
            if (lane == 0) wred[w] = wmax;
        } else if ((tid & 63) == 0) wred[w] = -INFINITY;
        __syncthreads();
        if (tid == 0)
            blkmax[blockIdx.x] = fmaxf(fmaxf(wred[0], wred[1]), fmaxf(wred[2], wred[3]));
    } else {
        // ---------- bucket path: count + partition edges by dst octant ----------
        int bb = blockIdx.x - EMB_B;
        int beg = bb * BCHUNK;
        int end = min(beg + BCHUNK, N_EDGES);
        if (tid < 8) scnt[tid] = 0u;
        __syncthreads();
        for (int base = beg; base < end; base += 256) {
            int e = base + tid;
            if (e < end) {
                unsigned src = (unsigned)__builtin_nontemporal_load(ei + e);
                unsigned dst = (unsigned)__builtin_nontemporal_load(ei + N_EDGES + e);
                atomicAdd(&counts[dst], 1u);
                int oct = (int)(dst / OCT_N);
                unsigned p = atomicAdd(&scnt[oct], 1u);
                if (p < SB_CAP)
                    sbuf[oct][p] = ((unsigned long long)dst << 32) | src;
            }
        }
        __syncthreads();
        if (tid < 8) {
            unsigned c = min(scnt[tid], (unsigned)SB_CAP);
            scnt[tid] = c;
            sbase[tid] = atomicAdd(&tail[tid], c);
        }
        __syncthreads();
        for (int o = 0; o < 8; ++o) {
            unsigned c = scnt[o], b = sbase[o];
            unsigned long long* dstp = oct_buf + (size_t)o * OCT_CAP;
            for (unsigned i = tid; i < c; i += 256) {
                unsigned pos = b + i;
                if (pos < OCT_CAP)
                    __builtin_nontemporal_store(sbuf[o][i], dstp + pos);
            }
        }
    }
}

// ---- two-level scan (counts+1 per node for the self-loop) ----
__global__ __launch_bounds__(1024) void scan_block(
    const unsigned* __restrict__ counts,
    unsigned* __restrict__ excl, unsigned* __restrict__ partial)
{
    __shared__ unsigned wt[16], wo[16];
    int tid = threadIdx.x, lane = tid & 63, wid = tid >> 6;
    int i = blockIdx.x * 1024 + tid;
    unsigned v = (i < N_NODES) ? (counts[i] + 1u) : 0u;
    unsigned xs = v;
#pragma unroll
    for (int off = 1; off < 64; off <<= 1) {
        unsigned t = __shfl_up(xs, off, 64);
        if (lane >= off) xs += t;
    }
    if (lane == 63) wt[wid] = xs;
    __syncthreads();
    if (tid == 0) {
        unsigned run = 0;
        for (int w = 0; w < 16; ++w) { wo[w] = run; run += wt[w]; }
        partial[blockIdx.x] = run;
    }
    __syncthreads();
    if (i < N_NODES) excl[i] = wo[wid] + xs - v;
}

// ---- finalize scan; place self-loop; init pool; reduce As1 (block 1) ----
__global__ __launch_bounds__(256) void scan_add(
    const unsigned* __restrict__ excl, const unsigned* __restrict__ partial,
    unsigned* __restrict__ row_ptr, unsigned* __restrict__ cursor,
    int* __restrict__ csr_src, unsigned* __restrict__ g_enc,
    const float* __restrict__ blkmax1, float* __restrict__ As1)
{
    __shared__ float sm[4];
    int tid = threadIdx.x, lane = tid & 63;
    int bg = blockIdx.x >> 2;
    unsigned pv = (lane < bg) ? partial[lane] : 0u;   // bg <= 48 < 64
#pragma unroll
    for (int off = 32; off; off >>= 1) pv += __shfl_xor(pv, off, 64);
    int i = blockIdx.x * 256 + tid;
    if (i < N_NODES) {
        unsigned r = excl[i] + pv;
        row_ptr[i] = r;
        csr_src[r] = i;          // self-loop occupies the first slot
        cursor[i]  = r + 1;
    }
    if (i == 0) row_ptr[N_NODES] = E_TOT;
    if (blockIdx.x == 0) {
        for (int j = tid; j < N_GRAPHS * HIDDEN; j += 256)
            g_enc[j] = fenc(-INFINITY);
    }
    if (blockIdx.x == 1) {
        float m = -INFINITY;
        for (int j = tid; j < EMB_B; j += 256) m = fmaxf(m, blkmax1[j]);
#pragma unroll
        for (int off = 32; off; off >>= 1) m = fmaxf(m, __shfl_xor(m, off, 64));
        if (lane == 0) sm[tid >> 6] = m;
        __syncthreads();
        if (tid == 0)
            As1[0] = fmaxf(fmaxf(sm[0], sm[1]), fmaxf(sm[2], sm[3]));
    }
}

// ---- scatter from per-octant buckets (L2-resident per XCD) ----
__global__ __launch_bounds__(256) void fill_buckets(
    const unsigned long long* __restrict__ oct_buf, const unsigned* __restrict__ tail,
    unsigned* __restrict__ cursor, int* __restrict__ csr_src)
{
    int oct = blockIdx.x & 7;        // round-robin XCD mapping
    int grp = blockIdx.x >> 3;       // 0..FILL_GRP-1
    unsigned cnt = min(tail[oct], (unsigned)OCT_CAP);
    unsigned per = (cnt + FILL_GRP - 1) / FILL_GRP;
    unsigned beg = grp * per;
    unsigned end = min(beg + per, cnt);
    const unsigned long long* seg = oct_buf + (size_t)oct * OCT_CAP;
    for (unsigned i = beg + threadIdx.x; i < end; i += 256) {
        unsigned long long pr = __builtin_nontemporal_load(seg + i);
        unsigned src = (unsigned)(pr & 0xffffffffu);
        unsigned dst = (unsigned)(pr >> 32);
        unsigned pos = atomicAdd(&cursor[dst], 1u);
        csr_src[pos] = (int)src;
    }
}

// ---- 1-block max-reduce of per-block maxima -> As[0] ----
__global__ __launch_bounds__(1024) void reduce_max(
    const float* __restrict__ in, int n, float* __restrict__ As)
{
    __shared__ float wm[16];
    int tid = threadIdx.x, lane = tid & 63, wid = tid >> 6;
    float m = -INFINITY;
    for (int i = tid; i < n; i += 1024) m = fmaxf(m, in[i]);
#pragma unroll
    for (int off = 32; off; off >>= 1) m = fmaxf(m, __shfl_xor(m, off, 64));
    if (lane == 0) wm[wid] = m;
    __syncthreads();
    if (tid == 0) {
        float r = -INFINITY;
        for (int w = 0; w < 16; ++w) r = fmaxf(r, wm[w]);
        As[0] = r;
    }
}

// ---- full-row weighted aggregation: lane = feature, readlane idx/wgt ----
__device__ __forceinline__ float agg_row(
    const __half* __restrict__ hmat,      // [N][64] fp16
    const float* __restrict__ asrc,
    const int* __restrict__ csr_src, int s0, int s1, float ad, float C,
    int lane, float& den_out)
{
    float acc0 = 0.f, acc1 = 0.f, acc2 = 0.f, acc3 = 0.f, sden = 0.f;
    for (int base = s0; base < s1; base += 64) {
        int i = base + lane;
        int idx = 0; float wgt = 0.f;
        if (i < s1) {
            idx = __builtin_nontemporal_load(csr_src + i);  // streamed once
            wgt = __expf(lrelu(asrc[idx] + ad) - C);
        }
        sden += wgt;
        int cnt = min(64, s1 - base);
        int j = 0;
        for (; j + 3 < cnt; j += 4) {        // 4 gathers in flight
            int sa = rli(idx, j);     float wa = rlf(wgt, j);
            int sb = rli(idx, j + 1); float wb = rlf(wgt, j + 1);
            int sc = rli(idx, j + 2); float wc = rlf(wgt, j + 2);
            int sd = rli(idx, j + 3); float wd = rlf(wgt, j + 3);
            acc0 = fmaf(wa, __half2float(hmat[(size_t)sa * 64 + lane]), acc0);
            acc1 = fmaf(wb, __half2float(hmat[(size_t)sb * 64 + lane]), acc1);
            acc2 = fmaf(wc, __half2float(hmat[(size_t)sc * 64 + lane]), acc2);
            acc3 = fmaf(wd, __half2float(hmat[(size_t)sd * 64 + lane]), acc3);
        }
        for (; j < cnt; ++j) {
            int sa = rli(idx, j); float wa = rlf(wgt, j);
            acc0 = fmaf(wa, __half2float(hmat[(size_t)sa * 64 + lane]), acc0);
        }
    }
#pragma unroll
    for (int off = 32; off; off >>= 1) sden += __shfl_xor(sden, off, 64);
    den_out = sden;
    return (acc0 + acc1) + (acc2 + acc3);
}

// ---- fused: GAT layer1 aggregate (+relu) + layer2 linear + alpha dots ----
__global__ __launch_bounds__(256) void agg1(
    const __half* __restrict__ hlin1,
    const float* __restrict__ asrc, const float* __restrict__ adst,
    const unsigned* __restrict__ row_ptr, const int* __restrict__ csr_src,
    const float* __restrict__ As1, const float* __restrict__ c1b,
    const float* __restrict__ c2w, const float* __restrict__ a2s, const float* __restrict__ a2d,
    __half* __restrict__ hlin2, float* __restrict__ asrc2, float* __restrict__ adst2,
    float* __restrict__ blkmax)
{
    __shared__ float wred[4];
    int lane = threadIdx.x & 63, w = threadIdx.x >> 6;
    int d = blockIdx.x * 4 + w;
    int s0 = (int)row_ptr[d], s1 = (int)row_ptr[d + 1];
    float ad = adst[d];
    float C = lrelu(As1[0] + ad);        // >= every edge's e (global asrc max)
    float den;
    float acc = agg_row(hlin1, asrc, csr_src, s0, s1, ad, C, lane, den);
    float v = fmaxf(acc / (den + 1e-30f) + c1b[lane], 0.f);   // + bias, relu
    float hl = 0.f;
#pragma unroll 8
    for (int k = 0; k < 64; ++k)
        hl = fmaf(rlf(v, k), c2w[k * 64 + lane], hl);
    hlin2[(size_t)d * 64 + lane] = __float2half(hl);
    float ps = hl * a2s[lane], pd = hl * a2d[lane];
#pragma unroll
    for (int off = 32; off; off >>= 1) {
        ps += __shfl_xor(ps, off, 64);
        pd += __shfl_xor(pd, off, 64);
    }
    if (lane == 0) { asrc2[d] = ps; adst2[d] = pd; wred[w] = ps; }
    __syncthreads();
    if (threadIdx.x == 0)
        blkmax[blockIdx.x] = fmaxf(fmaxf(wred[0], wred[1]), fmaxf(wred[2], wred[3]));
}

// ---- fused: GAT layer2 aggregate + bias + global max pool ----
__global__ __launch_bounds__(256) void agg2_pool(
    const __half* __restrict__ hlin2,
    const float* __restrict__ asrc, const float* __restrict__ adst,
    const unsigned* __restrict__ row_ptr, const int* __restrict__ csr_src,
    const float* __restrict__ As2, const float* __restrict__ c2b,
    const int* __restrict__ batch, unsigned* __restrict__ g_enc)
{
    int lane = threadIdx.x & 63;
    int d = blockIdx.x * 4 + (threadIdx.x >> 6);
    int s0 = (int)row_ptr[d], s1 = (int)row_ptr[d + 1];
    float ad = adst[d];
    float C = lrelu(As2[0] + ad);
    float den;
    float acc = agg_row(hlin2, asrc, csr_src, s0, s1, ad, C, lane, den);
    float v = acc / (den + 1e-30f) + c2b[lane];   // no relu
    atomicMax(&g_enc[batch[d] * 64 + lane], fenc(v));
}

// ---- readout MLP: wave per graph ----
__global__ __launch_bounds__(256) void readout(
    const unsigned* __restrict__ g_enc,
    const float* __restrict__ fc1w, const float* __restrict__ fc1b,
    const float* __restrict__ fc2w, const float* __restrict__ fc2b,
    float* __restrict__ out)
{
    int lane = threadIdx.x & 63;
    int gi = blockIdx.x * 4 + (threadIdx.x >> 6);
    float gv = fdec(g_enc[gi * 64 + lane]);
    float a = fc1b[lane];
#pragma unroll 8
    for (int k = 0; k < 64; ++k)
        a = fmaf(rlf(gv, k), fc1w[k * 64 + lane], a);
    a = fmaxf(a, 0.f) * fc2w[lane];
#pragma unroll
    for (int off = 32; off; off >>= 1) a += __shfl_xor(a, off, 64);
    if (lane == 0) out[gi] = a + fc2b[0];
}

extern "C" void kernel_launch(void* const* d_in, const int* in_sizes, int n_in,
                              void* d_out, int out_size, void* d_ws, size_t ws_size,
                              hipStream_t stream)
{
    const float* x      = (const float*)d_in[0];
    const int*   ei     = (const int*)d_in[1];
    // d_in[2] edge_attr: dead value in reference, never read
    const int*   batch  = (const int*)d_in[3];
    const float* n_w1   = (const float*)d_in[4];
    const float* n_b1   = (const float*)d_in[5];
    const float* n_w2   = (const float*)d_in[6];
    const float* n_b2   = (const float*)d_in[7];
    // d_in[8..11] edge MLP weights: dead
    const float* c1_w    = (const float*)d_in[12];
    const float* c1_asrc = (const float*)d_in[13];
    const float* c1_adst = (const float*)d_in[14];
    const float* c1_b    = (const float*)d_in[15];
    const float* c2_w    = (const float*)d_in[16];
    const float* c2_asrc = (const float*)d_in[17];
    const float* c2_adst = (const float*)d_in[18];
    const float* c2_b    = (const float*)d_in[19];
    const float* fc1_w   = (const float*)d_in[20];
    const float* fc1_b   = (const float*)d_in[21];
    const float* fc2_w   = (const float*)d_in[22];
    const float* fc2_b   = (const float*)d_in[23];
    float* out = (float*)d_out;

    // workspace carve (256B aligned)
    char* ws = (char*)d_ws;
    size_t off = 0;
    auto alloc = [&](size_t bytes) -> void* {
        off = (off + 255) & ~(size_t)255;
        void* p = ws + off;
        off += bytes;
        return p;
    };
    unsigned* counts  = (unsigned*)alloc(sizeof(unsigned) * (N_NODES + 64)); // +tail
    unsigned* tail    = counts + N_NODES;
    unsigned* excl    = (unsigned*)alloc(sizeof(unsigned) * N_NODES);
    unsigned* partial = (unsigned*)alloc(sizeof(unsigned) * (NB_SCAN + 1));
    unsigned* row_ptr = (unsigned*)alloc(sizeof(unsigned) * (N_NODES + 1));
    unsigned* cursor  = (unsigned*)alloc(sizeof(unsigned) * N_NODES);
    int*      csr_src = (int*)alloc(sizeof(int) * E_TOT);
    unsigned long long* oct_buf =
        (unsigned long long*)alloc(sizeof(unsigned long long) * 8ull * OCT_CAP);
    __half*   hlin1   = (__half*)alloc(sizeof(__half) * (size_t)N_NODES * 64);
    __half*   hlin2   = (__half*)alloc(sizeof(__half) * (size_t)N_NODES * 64);
    float*    asrc1   = (float*)alloc(sizeof(float) * N_NODES);
    float*    adst1   = (float*)alloc(sizeof(float) * N_NODES);
    float*    asrc2   = (float*)alloc(sizeof(float) * N_NODES);
    float*    adst2   = (float*)alloc(sizeof(float) * N_NODES);
    unsigned* g_enc   = (unsigned*)alloc(sizeof(unsigned) * N_GRAPHS * HIDDEN);
    float*    w2c1    = (float*)alloc(sizeof(float) * 64 * 64);
    float*    b2c1    = (float*)alloc(sizeof(float) * 64);
    float*    blkmax1 = (float*)alloc(sizeof(float) * EMB_B);
    float*    blkmax2 = (float*)alloc(sizeof(float) * AGG_B);
    float*    As1     = (float*)alloc(sizeof(float) * 2);
    float*    As2     = (float*)alloc(sizeof(float) * 2);

    // zero counts + tail in one memset
    hipMemsetAsync(counts, 0, sizeof(unsigned) * (N_NODES + 64), stream);
    fold_w<<<1, 256, 0, stream>>>(n_w2, n_b2, c1_w, w2c1, b2c1);

    // fused embed + edge bucketing (independent work co-scheduled)
    embed_bucket<<<EMB_B + BUCKET_B, 256, 0, stream>>>(
        x, n_w1, n_b1, w2c1, b2c1, c1_asrc, c1_adst,
        hlin1, asrc1, adst1, blkmax1,
        ei, counts, tail, oct_buf);

    scan_block<<<NB_SCAN, 1024, 0, stream>>>(counts, excl, partial);
    scan_add<<<(N_NODES + 255) / 256, 256, 0, stream>>>(
        excl, partial, row_ptr, cursor, csr_src, g_enc, blkmax1, As1);
    fill_buckets<<<8 * FILL_GRP, 256, 0, stream>>>(oct_buf, tail, cursor, csr_src);

    agg1<<<AGG_B, 256, 0, stream>>>(
        hlin1, asrc1, adst1, row_ptr, csr_src, As1,
        c1_b, c2_w, c2_asrc, c2_adst, hlin2, asrc2, adst2, blkmax2);
    reduce_max<<<1, 1024, 0, stream>>>(blkmax2, AGG_B, As2);
    agg2_pool<<<AGG_B, 256, 0, stream>>>(
        hlin2, asrc2, adst2, row_ptr, csr_src, As2, c2_b, batch, g_enc);
    readout<<<N_GRAPHS / 4, 256, 0, stream>>>(g_enc, fc1_w, fc1_b, fc2_w, fc2_b, out);
}